// Round 5
// baseline (361.828 us; speedup 1.0000x reference)
//
#include <hip/hip_runtime.h>
#include <hip/hip_cooperative_groups.h>
#include <math.h>

namespace cg = cooperative_groups;

#define L_LEN  262144          // L  = 2^18
#define N2L    524288          // 2L = 2^19
#define NST    64
#define TPB    256
#define GRID   256
#define PI2F   6.2831853071795864769f
#define PIF    3.1415926535897932385f

__device__ inline float2 cmul(float2 a, float2 b) {
    return make_float2(a.x*b.x - a.y*b.y, a.x*b.y + a.y*b.x);
}

// ---- NF independent length-M FFTs in LDS, radix-4 Stockham (+ final radix-2
// when M = 2*4^k). Layout: buf[f*M + i]. Natural order in, natural order out.
// sgn=-1 fwd, +1 inv (unscaled). Starts AND ends with __syncthreads(), so
// callers may fill b0 right before and read the result right after.
template<int M, int NF>
__device__ float2* lds_fft_r4(float2* b0, float2* b1, float sgn) {
    float2* src = b0; float2* dst = b1;
    int Ns = 1;
    while (Ns * 4 <= M) {
        __syncthreads();
        const int NB = NF * (M / 4);
        for (int bi = threadIdx.x; bi < NB; bi += TPB) {
            int f = bi / (M / 4);
            int j = bi & (M / 4 - 1);
            int r = j & (Ns - 1);
            const float2* s = src + f * M;
            float2 x0 = s[j];
            float2 x1 = s[j +     (M/4)];
            float2 x2 = s[j + 2 * (M/4)];
            float2 x3 = s[j + 3 * (M/4)];
            float ang = sgn * PI2F * ((float)r / (float)(4 * Ns));
            float sn, cs; __sincosf(ang, &sn, &cs);
            float2 w1 = make_float2(cs, sn);
            float2 w2 = cmul(w1, w1);
            float2 w3 = cmul(w2, w1);
            x1 = cmul(x1, w1); x2 = cmul(x2, w2); x3 = cmul(x3, w3);
            float2 t0 = make_float2(x0.x + x2.x, x0.y + x2.y);
            float2 t1 = make_float2(x0.x - x2.x, x0.y - x2.y);
            float2 t2 = make_float2(x1.x + x3.x, x1.y + x3.y);
            float2 t3 = make_float2(x1.x - x3.x, x1.y - x3.y);
            float2* d = dst + f * M + ((j - r) << 2) + r;
            d[0]      = make_float2(t0.x + t2.x, t0.y + t2.y);
            d[Ns]     = make_float2(t1.x - sgn * t3.y, t1.y + sgn * t3.x);
            d[2 * Ns] = make_float2(t0.x - t2.x, t0.y - t2.y);
            d[3 * Ns] = make_float2(t1.x + sgn * t3.y, t1.y - sgn * t3.x);
        }
        float2* t = src; src = dst; dst = t;
        Ns <<= 2;
    }
    if (Ns < M) {              // final radix-2, Ns == M/2, r == j
        __syncthreads();
        const int NB = NF * (M / 2);
        for (int bi = threadIdx.x; bi < NB; bi += TPB) {
            int f = bi / (M / 2);
            int j = bi & (M / 2 - 1);
            const float2* s = src + f * M;
            float2 a = s[j];
            float2 b = s[j + M / 2];
            float ang = sgn * PI2F * ((float)j / (float)M);
            float sn, cs; __sincosf(ang, &sn, &cs);
            float2 wb = make_float2(cs * b.x - sn * b.y, cs * b.y + sn * b.x);
            float2* d = dst + f * M + j;
            d[0]     = make_float2(a.x + wb.x, a.y + wb.y);
            d[M / 2] = make_float2(a.x - wb.x, a.y - wb.y);
        }
        float2* t = src; src = dst; dst = t;
    }
    __syncthreads();
    return src;
}

// ===================== phase bodies (shared by mono + fallback) ============
// Layouts (column-major so every global READ is a contiguous 4KB run):
//   T1[k2*512 + n1], k2<512   T2[k2*512 + n1], k2<1024   T3[k2*512 + n1], k2<1024

// P1: atRoots inline + iFFT-L pass1, rows n1 = bx, bx+256 (NF=2)
__device__ void phase1(int bx, float2* B0, float2* B1,
    const float* __restrict__ Lre, const float* __restrict__ Lim,
    const float* __restrict__ Pre, const float* __restrict__ Pim,
    const float* __restrict__ Bre, const float* __restrict__ Bim,
    const float* __restrict__ Cri, const float* __restrict__ lstp,
    float2* __restrict__ T1)
{
    __shared__ float  sLr[NST], sLi[NST];
    __shared__ float2 sv00[NST], sv01[NST], sv10[NST], sv11[NST];
    int t = threadIdx.x;
    if (t < NST) {
        float lr = Lre[t], li = Lim[t];
        float pr = Pre[t], pi = Pim[t];
        float br = Bre[t], bi = Bim[t];
        float cr = Cri[2*t], ci = Cri[2*t+1];
        sLr[t] = lr; sLi[t] = li;
        sv00[t] = make_float2(cr*br + ci*bi, cr*bi - ci*br);   // conj(C)*B
        sv01[t] = make_float2(cr*pr + ci*pi, cr*pi - ci*pr);   // conj(C)*P
        sv10[t] = make_float2(pr*br + pi*bi, pr*bi - pi*br);   // conj(P)*B
        sv11[t] = make_float2(pr*pr + pi*pi, 0.f);             // conj(P)*P
    }
    __syncthreads();
    float G2 = 2.0f / expf(lstp[0]);
    for (int i = t; i < 1024; i += TPB) {
        int uu = i >> 9, e = i & 511;
        int n1 = bx + (uu << 8);
        int j  = n1 + (e << 9);
        // (1-Om)/(1+Om) = i*tan(pi j/L); c = 1+i*tan; g = i*G2*tan
        float h = PIF * ((float)j * (1.0f / (float)L_LEN));
        float sn, cs; __sincosf(h, &sn, &cs);
        float tn = sn * __frcp_rn(cs);
        // pole guard (j=L/2: HW cos is exactly 0 -> inf*0=NaN without this)
        tn = fminf(fmaxf(tn, -1e7f), 1e7f);
        float gi = G2 * tn;
        float2 k00 = make_float2(0,0), k01 = make_float2(0,0);
        float2 k10 = make_float2(0,0), k11 = make_float2(0,0);
        #pragma unroll
        for (int n = 0; n < NST; ++n) {
            float dx = -sLr[n];
            float dy = gi - sLi[n];
            float iv = __frcp_rn(dx*dx + dy*dy);
            float rx = dx * iv, ry = -dy * iv;
            float2 v;
            v = sv00[n]; k00.x += rx*v.x - ry*v.y; k00.y += rx*v.y + ry*v.x;
            v = sv01[n]; k01.x += rx*v.x - ry*v.y; k01.y += rx*v.y + ry*v.x;
            v = sv10[n]; k10.x += rx*v.x - ry*v.y; k10.y += rx*v.y + ry*v.x;
            v = sv11[n]; k11.x += rx*v.x;          k11.y += ry*v.x;
        }
        float ax = 1.f + k11.x, ay = k11.y;
        float im = 1.f / (ax*ax + ay*ay);
        float tx = k01.x*k10.x - k01.y*k10.y;
        float ty = k01.x*k10.y + k01.y*k10.x;
        float wx = k00.x - (tx*ax + ty*ay) * im;
        float wy = k00.y - (ty*ax - tx*ay) * im;
        B0[i] = make_float2(wx - tn*wy, wy + tn*wx);   // (1+i*tn)*w
    }
    float2* r = lds_fft_r4<512, 2>(B0, B1, +1.f);
    const float invL = 1.0f / (float)L_LEN;
    for (int i = t; i < 1024; i += TPB) {
        int uu = i >> 9, e = i & 511;
        int n1 = bx + (uu << 8);
        float ang = PI2F * ((float)(n1 * e) * invL);   // n1*e < 2^18, exact
        float sn, cs; __sincosf(ang, &sn, &cs);
        T1[(e << 9) + n1] = cmul(make_float2(cs, sn), r[i]);   // col-major
    }
}

// P2: iFFT-L pass2 + z-build + fwd-2L pass1, cols/rows c = bx, bx+256 (NF=2)
__device__ void phase2(int bx, float2* B0, float2* B1,
    const float2* __restrict__ T1, const float* __restrict__ uin,
    float2* __restrict__ T2)
{
    int t = threadIdx.x;
    for (int i = t; i < 1024; i += TPB) {
        int uu = i >> 9, e = i & 511;
        B0[i] = T1[((bx + (uu << 8)) << 9) + e];       // contiguous
    }
    float2* r = lds_fft_r4<512, 2>(B0, B1, +1.f);
    float2* o = (r == B0) ? B1 : B0;
    const float invL = 1.0f / (float)L_LEN;
    for (int i = t; i < 1024; i += TPB) {
        int uu = i >> 9, k1 = i & 511;
        int c   = bx + (uu << 8);
        int idx = c + (k1 << 9);                       // time index
        o[(uu << 10) + k1]       = make_float2(uin[idx], r[i].x * invL); // z=u+iK
        o[(uu << 10) + 512 + k1] = make_float2(0.f, 0.f);                // pad
    }
    float2* r2 = lds_fft_r4<1024, 2>(o, r, -1.f);
    const float inv2L = 1.0f / (float)N2L;
    for (int i = t; i < 2048; i += TPB) {
        int uu = i >> 10, k2 = i & 1023;
        int c = bx + (uu << 8);                        // n1 of the 2L FFT
        float ang = -PI2F * ((float)(c * k2) * inv2L); // c*k2 < 2^20, exact
        float sn, cs; __sincosf(ang, &sn, &cs);
        T2[(k2 << 9) + c] = cmul(make_float2(cs, sn), r2[i]);  // col-major
    }
}

// P3: fwd-2L pass2 x4 mirror-closed cols + Hermitian combine + inv-2L pass1 x2
__device__ void phase3(int bx, float2* B0, float2* B1,
    const float2* __restrict__ T2, float2* __restrict__ T3)
{
    int t = threadIdx.x;
    const int q = bx;
    int cols[4];
    if (q == 0) { cols[0]=0; cols[1]=512;   cols[2]=256;   cols[3]=768; }
    else        { cols[0]=q; cols[1]=512+q; cols[2]=512-q; cols[3]=1024-q; }
    for (int i = t; i < 2048; i += TPB) {
        int f = i >> 9, e = i & 511;
        B0[i] = T2[(cols[f] << 9) + e];                // contiguous runs
    }
    float2* r = lds_fft_r4<512, 4>(B0, B1, -1.f);
    float2* o = (r == B0) ? B1 : B0;
    // W[col_f + 1024*k1] = U*Kf via mirror; write into inv-pass1 input order:
    // seq (f>>1) holds W[n1 + 512*n2] with n1 = rowA/rowB
    for (int i = t; i < 2048; i += TPB) {
        int f = i >> 9, k1 = i & 511;
        int mf, m;
        if (q) { mf = 3 - f;               m = 511 - k1; }
        else   { mf = (f < 2) ? f : 5 - f; m = (f == 0) ? ((512 - k1) & 511)
                                                        : (511 - k1); }
        float2 zp = r[(f  << 9) + k1];
        float2 zq = r[(mf << 9) + m];
        float2 U  = make_float2(0.5f*(zp.x + zq.x), 0.5f*(zp.y - zq.y));
        float2 dd = make_float2(zp.x - zq.x, zp.y + zq.y);   // zp - conj(zq)
        float2 Kf = make_float2(0.5f*dd.y, -0.5f*dd.x);      // dd * (-i/2)
        o[((f >> 1) << 10) + (k1 << 1) + (f & 1)] = cmul(U, Kf);
    }
    float2* r2 = lds_fft_r4<1024, 2>(o, r, +1.f);
    const float inv2L = 1.0f / (float)N2L;
    for (int i = t; i < 2048; i += TPB) {
        int s = i >> 10, k2 = i & 1023;
        int n1 = s ? ((q == 0) ? 256 : 512 - q) : q;
        float ang = PI2F * ((float)(n1 * k2) * inv2L);
        float sn, cs; __sincosf(ang, &sn, &cs);
        T3[(k2 << 9) + n1] = cmul(make_float2(cs, sn), r2[(s << 10) + k2]);
    }
}

// P4: inv-2L pass2, cols 4bx..4bx+3 (NF=4) + scale + D*u + store y
__device__ void phase4(int bx, float2* B0, float2* B1,
    const float2* __restrict__ T3, const float* __restrict__ uin,
    const float* __restrict__ Dp, float* __restrict__ outp)
{
    int t = threadIdx.x;
    int c0 = bx << 2;
    for (int i = t; i < 2048; i += TPB) {
        int f = i >> 9, e = i & 511;
        B0[i] = T3[((c0 + f) << 9) + e];               // contiguous
    }
    float2* r = lds_fft_r4<512, 4>(B0, B1, +1.f);
    const float inv2L = 1.0f / (float)N2L;
    float D = Dp[0];
    for (int i = t; i < 1024; i += TPB) {              // k1<256 -> idx < L
        int f = i >> 8, k1 = i & 255;
        int idx = (c0 + f) + (k1 << 10);
        outp[idx] = fmaf(D, uin[idx], r[(f << 9) + k1].x * inv2L);
    }
}

// ===================== mono cooperative kernel =============================
__global__ __launch_bounds__(TPB) void s4_mono(
    const float* u,
    const float* Lre, const float* Lim, const float* Pre, const float* Pim,
    const float* Bre, const float* Bim, const float* Cri, const float* Dp,
    const float* lstp, float* out, float2* T1, float2* T2, float2* T3)
{
    cg::grid_group grid = cg::this_grid();
    __shared__ float2 B0[2048], B1[2048];
    int bx = blockIdx.x;
    phase1(bx, B0, B1, Lre, Lim, Pre, Pim, Bre, Bim, Cri, lstp, T1);
    __threadfence(); grid.sync();
    phase2(bx, B0, B1, T1, u, T2);
    __threadfence(); grid.sync();
    phase3(bx, B0, B1, T2, T3);
    __threadfence(); grid.sync();
    phase4(bx, B0, B1, T3, u, Dp, out);
}

// ===================== fallback: same phases as 4 plain kernels ============
__global__ __launch_bounds__(TPB) void k_p1(
    const float* Lre, const float* Lim, const float* Pre, const float* Pim,
    const float* Bre, const float* Bim, const float* Cri, const float* lstp,
    float2* T1)
{
    __shared__ float2 B0[2048], B1[2048];
    phase1(blockIdx.x, B0, B1, Lre, Lim, Pre, Pim, Bre, Bim, Cri, lstp, T1);
}
__global__ __launch_bounds__(TPB) void k_p2(
    const float2* T1, const float* u, float2* T2)
{
    __shared__ float2 B0[2048], B1[2048];
    phase2(blockIdx.x, B0, B1, T1, u, T2);
}
__global__ __launch_bounds__(TPB) void k_p3(const float2* T2, float2* T3)
{
    __shared__ float2 B0[2048], B1[2048];
    phase3(blockIdx.x, B0, B1, T2, T3);
}
__global__ __launch_bounds__(TPB) void k_p4(
    const float2* T3, const float* u, const float* Dp, float* out)
{
    __shared__ float2 B0[2048], B1[2048];
    phase4(blockIdx.x, B0, B1, T3, u, Dp, out);
}

extern "C" void kernel_launch(void* const* d_in, const int* in_sizes, int n_in,
                              void* d_out, int out_size, void* d_ws, size_t ws_size,
                              hipStream_t stream) {
    const float* u    = (const float*)d_in[0];
    const float* Lre  = (const float*)d_in[1];
    const float* Lim  = (const float*)d_in[2];
    const float* Pre  = (const float*)d_in[3];
    const float* Pim  = (const float*)d_in[4];
    const float* Bre  = (const float*)d_in[5];
    const float* Bim  = (const float*)d_in[6];
    const float* Cri  = (const float*)d_in[7];
    const float* Dp   = (const float*)d_in[8];
    const float* lstp = (const float*)d_in[9];
    float* out = (float*)d_out;

    char* ws = (char*)d_ws;                       // 10 MB used
    float2* T1 = (float2*)(ws);                   // 512x512  cm (2 MB)
    float2* T2 = (float2*)(ws + (2u << 20));      // 1024x512 cm (4 MB)
    float2* T3 = (float2*)(ws + (6u << 20));      // 1024x512 cm (4 MB)

    void* args[] = { (void*)&u, (void*)&Lre, (void*)&Lim, (void*)&Pre,
                     (void*)&Pim, (void*)&Bre, (void*)&Bim, (void*)&Cri,
                     (void*)&Dp, (void*)&lstp, (void*)&out,
                     (void*)&T1, (void*)&T2, (void*)&T3 };
    hipError_t err = hipLaunchCooperativeKernel(
        s4_mono, dim3(GRID), dim3(TPB), args, 0, stream);
    if (err != hipSuccess) {
        // deterministic fallback: identical math, 4 plain dispatches
        k_p1<<<GRID, TPB, 0, stream>>>(Lre,Lim,Pre,Pim,Bre,Bim,Cri,lstp,T1);
        k_p2<<<GRID, TPB, 0, stream>>>(T1, u, T2);
        k_p3<<<GRID, TPB, 0, stream>>>(T2, T3);
        k_p4<<<GRID, TPB, 0, stream>>>(T3, u, Dp, out);
    }
}

// Round 6
// 135.163 us; speedup vs baseline: 2.6770x; 2.6770x over previous
//
#include <hip/hip_runtime.h>
#include <math.h>

#define L_LEN  262144          // L = 2^18 = 512*512
#define NST    64
#define TPB    256
#define PI2F   6.2831853071795864769f
#define PIF    3.1415926535897932385f

__device__ inline float2 cmul(float2 a, float2 b) {
    return make_float2(a.x*b.x - a.y*b.y, a.x*b.y + a.y*b.x);
}

// NF independent length-M FFTs in LDS, radix-4 Stockham + final radix-2.
// Layout buf[f*M+i]; natural in/out; sgn=-1 fwd, +1 inv (unscaled).
// Starts and ends with __syncthreads().
template<int M, int NF>
__device__ float2* lds_fft_r4(float2* b0, float2* b1, float sgn) {
    float2* src = b0; float2* dst = b1;
    int Ns = 1;
    while (Ns * 4 <= M) {
        __syncthreads();
        const int NB = NF * (M / 4);
        for (int bi = threadIdx.x; bi < NB; bi += TPB) {
            int f = bi / (M / 4);
            int j = bi & (M / 4 - 1);
            int r = j & (Ns - 1);
            const float2* s = src + f * M;
            float2 x0 = s[j];
            float2 x1 = s[j +     (M/4)];
            float2 x2 = s[j + 2 * (M/4)];
            float2 x3 = s[j + 3 * (M/4)];
            float ang = sgn * PI2F * ((float)r / (float)(4 * Ns));
            float sn, cs; __sincosf(ang, &sn, &cs);
            float2 w1 = make_float2(cs, sn);
            float2 w2 = cmul(w1, w1);
            float2 w3 = cmul(w2, w1);
            x1 = cmul(x1, w1); x2 = cmul(x2, w2); x3 = cmul(x3, w3);
            float2 t0 = make_float2(x0.x + x2.x, x0.y + x2.y);
            float2 t1 = make_float2(x0.x - x2.x, x0.y - x2.y);
            float2 t2 = make_float2(x1.x + x3.x, x1.y + x3.y);
            float2 t3 = make_float2(x1.x - x3.x, x1.y - x3.y);
            float2* d = dst + f * M + ((j - r) << 2) + r;
            d[0]      = make_float2(t0.x + t2.x, t0.y + t2.y);
            d[Ns]     = make_float2(t1.x - sgn * t3.y, t1.y + sgn * t3.x);
            d[2 * Ns] = make_float2(t0.x - t2.x, t0.y - t2.y);
            d[3 * Ns] = make_float2(t1.x + sgn * t3.y, t1.y - sgn * t3.x);
        }
        float2* t = src; src = dst; dst = t;
        Ns <<= 2;
    }
    if (Ns < M) {
        __syncthreads();
        const int NB = NF * (M / 2);
        for (int bi = threadIdx.x; bi < NB; bi += TPB) {
            int f = bi / (M / 2);
            int j = bi & (M / 2 - 1);
            const float2* s = src + f * M;
            float2 a = s[j];
            float2 b = s[j + M / 2];
            float ang = sgn * PI2F * ((float)j / (float)M);
            float sn, cs; __sincosf(ang, &sn, &cs);
            float2 wb = make_float2(cs * b.x - sn * b.y, cs * b.y + sn * b.x);
            float2* d = dst + f * M + j;
            d[0]     = make_float2(a.x + wb.x, a.y + wb.y);
            d[M / 2] = make_float2(a.x - wb.x, a.y - wb.y);
        }
        float2* t = src; src = dst; dst = t;
    }
    __syncthreads();
    return src;
}

// Layouts: all staging arrays are 512x512 float2, indexed [col*512 + row]
// so every pass-2/pointwise READ is a contiguous 4KB run; pass-1 stores
// scatter in 16B pairs (adjacent columns per block).

// ---- kA: blocks 0..255: A=atRoots inline (+store Acm) + ifft-L pass1 -> T_K
//          blocks 256..511: u pass1 (fwd) -> T_U.  Col pair c0=2*(bx&255).
__global__ __launch_bounds__(TPB) void kA(
    const float* __restrict__ u,
    const float* __restrict__ Lre, const float* __restrict__ Lim,
    const float* __restrict__ Pre, const float* __restrict__ Pim,
    const float* __restrict__ Bre, const float* __restrict__ Bim,
    const float* __restrict__ Cri, const float* __restrict__ lstp,
    float2* __restrict__ Acm, float2* __restrict__ T_K, float2* __restrict__ T_U)
{
    __shared__ float2 b0[1024], b1[1024];
    __shared__ float  sLr[NST], sLi[NST];
    __shared__ float2 sv00[NST], sv01[NST], sv10[NST], sv11[NST];
    const int t = threadIdx.x, bx = blockIdx.x;
    const int c0 = (bx & 255) << 1;
    const float invL = 1.0f / (float)L_LEN;
    if (bx < 256) {
        if (t < NST) {
            float lr = Lre[t], li = Lim[t];
            float pr = Pre[t], pi = Pim[t];
            float br = Bre[t], bi = Bim[t];
            float cr = Cri[2*t], ci = Cri[2*t+1];
            sLr[t] = lr; sLi[t] = li;
            sv00[t] = make_float2(cr*br + ci*bi, cr*bi - ci*br);
            sv01[t] = make_float2(cr*pr + ci*pi, cr*pi - ci*pr);
            sv10[t] = make_float2(pr*br + pi*bi, pr*bi - pi*br);
            sv11[t] = make_float2(pr*pr + pi*pi, 0.f);
        }
        __syncthreads();
        float G2 = 2.0f / expf(lstp[0]);
        for (int i = t; i < 1024; i += TPB) {
            int f = i >> 9, e = i & 511;
            int c = c0 + f;
            int m = c + (e << 9);
            float h = PIF * ((float)m * invL);
            float sn, cs; __sincosf(h, &sn, &cs);
            float tn = sn * __frcp_rn(cs);
            tn = fminf(fmaxf(tn, -1e7f), 1e7f);     // pole guard (m=L/2)
            float gi = G2 * tn;
            float2 k00 = make_float2(0,0), k01 = make_float2(0,0);
            float2 k10 = make_float2(0,0), k11 = make_float2(0,0);
            #pragma unroll
            for (int n = 0; n < NST; ++n) {
                float dx = -sLr[n];
                float dy = gi - sLi[n];
                float iv = __frcp_rn(dx*dx + dy*dy);
                float rx = dx * iv, ry = -dy * iv;
                float2 v;
                v = sv00[n]; k00.x += rx*v.x - ry*v.y; k00.y += rx*v.y + ry*v.x;
                v = sv01[n]; k01.x += rx*v.x - ry*v.y; k01.y += rx*v.y + ry*v.x;
                v = sv10[n]; k10.x += rx*v.x - ry*v.y; k10.y += rx*v.y + ry*v.x;
                v = sv11[n]; k11.x += rx*v.x;          k11.y += ry*v.x;
            }
            float ax = 1.f + k11.x, ay = k11.y;
            float im = 1.f / (ax*ax + ay*ay);
            float tx = k01.x*k10.x - k01.y*k10.y;
            float ty = k01.x*k10.y + k01.y*k10.x;
            float wx = k00.x - (tx*ax + ty*ay) * im;
            float wy = k00.y - (ty*ax - tx*ay) * im;
            float2 A = make_float2(wx - tn*wy, wy + tn*wx);   // (1+i*tan)*w
            Acm[(c << 9) + e] = A;                 // contiguous store
            b0[i] = A;
        }
        float2* r = lds_fft_r4<512, 2>(b0, b1, +1.f);
        for (int i = t; i < 1024; i += TPB) {
            int f = i & 1, k = i >> 1;
            int c = c0 + f;
            float ang = PI2F * ((float)(c * k) * invL);
            float sn, cs; __sincosf(ang, &sn, &cs);
            T_K[(k << 9) + c] = cmul(make_float2(cs, sn), r[(f << 9) + k]);
        }
    } else {
        for (int i = t; i < 1024; i += TPB) {       // paired 8B u gathers
            int f = i & 1, e = i >> 1;
            b0[(f << 9) + e] = make_float2(u[(c0 + f) + (e << 9)], 0.f);
        }
        float2* r = lds_fft_r4<512, 2>(b0, b1, -1.f);
        for (int i = t; i < 1024; i += TPB) {
            int f = i & 1, k = i >> 1;
            int c = c0 + f;
            float ang = -PI2F * ((float)(c * k) * invL);
            float sn, cs; __sincosf(ang, &sn, &cs);
            T_U[(k << 9) + c] = cmul(make_float2(cs, sn), r[(f << 9) + k]);
        }
    }
}

// ---- kB: blocks 0..255: ifft pass2 of T_K -> K(real) -> K*tw/L -> fwd pass1 -> T_Ko
//          blocks 256..511: u*tw -> fwd pass1 -> T_Uo
__global__ __launch_bounds__(TPB) void kB(
    const float* __restrict__ u, const float2* __restrict__ T_K,
    float2* __restrict__ T_Ko, float2* __restrict__ T_Uo)
{
    __shared__ float2 b0[1024], b1[1024];
    const int t = threadIdx.x, bx = blockIdx.x;
    const int c0 = (bx & 255) << 1;
    const float invL = 1.0f / (float)L_LEN;
    if (bx < 256) {
        for (int i = t; i < 1024; i += TPB)
            b0[i] = T_K[((c0 + (i >> 9)) << 9) + (i & 511)];   // contiguous
        float2* r = lds_fft_r4<512, 2>(b0, b1, +1.f);
        float2* o = (r == b0) ? b1 : b0;
        for (int i = t; i < 1024; i += TPB) {
            int f = i >> 9, o1 = i & 511;
            int n = (c0 + f) + (o1 << 9);
            float K = r[i].x * invL;               // Re(ifft) with 1/L
            float sn, cs; __sincosf(PIF * ((float)n * invL), &sn, &cs);
            o[i] = make_float2(K * cs, -K * sn);   // K * e^{-i pi n/L}
        }
        float2* r2 = lds_fft_r4<512, 2>(o, r, -1.f);
        for (int i = t; i < 1024; i += TPB) {
            int f = i & 1, k = i >> 1;
            int c = c0 + f;
            float ang = -PI2F * ((float)(c * k) * invL);
            float sn, cs; __sincosf(ang, &sn, &cs);
            T_Ko[(k << 9) + c] = cmul(make_float2(cs, sn), r2[(f << 9) + k]);
        }
    } else {
        for (int i = t; i < 1024; i += TPB) {
            int f = i & 1, e = i >> 1;
            int n = (c0 + f) + (e << 9);
            float uv = u[n];
            float sn, cs; __sincosf(PIF * ((float)n * invL), &sn, &cs);
            b0[(f << 9) + e] = make_float2(uv * cs, -uv * sn);  // u * tw
        }
        float2* r = lds_fft_r4<512, 2>(b0, b1, -1.f);
        for (int i = t; i < 1024; i += TPB) {
            int f = i & 1, k = i >> 1;
            int c = c0 + f;
            float ang = -PI2F * ((float)(c * k) * invL);
            float sn, cs; __sincosf(ang, &sn, &cs);
            T_Uo[(k << 9) + c] = cmul(make_float2(cs, sn), r[(f << 9) + k]);
        }
    }
}

// ---- kC: pass2 of T_U / T_Uo / T_Ko -> Ue / Uo / Ko (all contiguous I/O)
__global__ __launch_bounds__(TPB) void kC(
    const float2* __restrict__ T_U, const float2* __restrict__ T_Uo,
    const float2* __restrict__ T_Ko,
    float2* __restrict__ Ue, float2* __restrict__ Uo, float2* __restrict__ Ko)
{
    __shared__ float2 b0[1024], b1[1024];
    const int t = threadIdx.x, bx = blockIdx.x;
    const int s = bx >> 8;
    const int c0 = (bx & 255) << 1;
    const float2* Tin = (s == 0) ? T_U : (s == 1) ? T_Uo : T_Ko;
    float2*       Xo  = (s == 0) ? Ue  : (s == 1) ? Uo   : Ko;
    for (int i = t; i < 1024; i += TPB)
        b0[i] = Tin[((c0 + (i >> 9)) << 9) + (i & 511)];
    float2* r = lds_fft_r4<512, 2>(b0, b1, -1.f);
    for (int i = t; i < 1024; i += TPB)
        Xo[((c0 + (i >> 9)) << 9) + (i & 511)] = r[i];
}

// ---- kD: blocks 0..255: Ve = Ue * Herm(A) -> inv pass1 -> T_Ve
//          blocks 256..511: Vo = Uo * Ko    -> inv pass1 -> T_Vo
__global__ __launch_bounds__(TPB) void kD(
    const float2* __restrict__ Ue, const float2* __restrict__ Uo,
    const float2* __restrict__ Ko, const float2* __restrict__ Acm,
    float2* __restrict__ T_Ve, float2* __restrict__ T_Vo)
{
    __shared__ float2 b0[1024], b1[1024];
    const int t = threadIdx.x, bx = blockIdx.x;
    const int c0 = (bx & 255) << 1;
    const float invL = 1.0f / (float)L_LEN;
    if (bx < 256) {
        for (int i = t; i < 1024; i += TPB) {
            int f = i >> 9, k1 = i & 511;
            int c = c0 + f;
            float2 ue = Ue[(c << 9) + k1];
            float2 a  = Acm[(c << 9) + k1];
            int cm = (512 - c) & 511;
            int km = (c == 0) ? ((512 - k1) & 511) : (511 - k1);
            float2 am = Acm[(cm << 9) + km];
            // Kd_even[m] = fft(Re(ifft(A)))[m] = (A[m]+conj(A[L-m]))/2
            float2 ah = make_float2(0.5f * (a.x + am.x), 0.5f * (a.y - am.y));
            b0[i] = cmul(ue, ah);
        }
        float2* r = lds_fft_r4<512, 2>(b0, b1, +1.f);
        for (int i = t; i < 1024; i += TPB) {
            int f = i & 1, k = i >> 1;
            int c = c0 + f;
            float ang = PI2F * ((float)(c * k) * invL);
            float sn, cs; __sincosf(ang, &sn, &cs);
            T_Ve[(k << 9) + c] = cmul(make_float2(cs, sn), r[(f << 9) + k]);
        }
    } else {
        for (int i = t; i < 1024; i += TPB) {
            int f = i >> 9, k1 = i & 511;
            int c = c0 + f;
            b0[i] = cmul(Uo[(c << 9) + k1], Ko[(c << 9) + k1]);
        }
        float2* r = lds_fft_r4<512, 2>(b0, b1, +1.f);
        for (int i = t; i < 1024; i += TPB) {
            int f = i & 1, k = i >> 1;
            int c = c0 + f;
            float ang = PI2F * ((float)(c * k) * invL);
            float sn, cs; __sincosf(ang, &sn, &cs);
            T_Vo[(k << 9) + c] = cmul(make_float2(cs, sn), r[(f << 9) + k]);
        }
    }
}

// ---- kE: inv pass2 of T_Ve & T_Vo (NF=4 in one call) + combine + D*u + store
__global__ __launch_bounds__(TPB) void kE(
    const float2* __restrict__ T_Ve, const float2* __restrict__ T_Vo,
    const float* __restrict__ u, const float* __restrict__ Dp,
    float* __restrict__ out)
{
    __shared__ float2 b0[2048], b1[2048];
    const int t = threadIdx.x, bx = blockIdx.x;
    const int c0 = bx << 1;
    const float invL = 1.0f / (float)L_LEN;
    for (int i = t; i < 1024; i += TPB) {
        int f = i >> 9, m1 = i & 511;
        b0[i]        = T_Ve[((c0 + f) << 9) + m1];
        b0[i + 1024] = T_Vo[((c0 + f) << 9) + m1];
    }
    float2* r = lds_fft_r4<512, 4>(b0, b1, +1.f);   // f<2: yE, f>=2: yO
    const float sc = 0.5f * invL;                   // 1/(2L)
    const float D = Dp[0];
    for (int i = t; i < 1024; i += TPB) {
        int f = i & 1, o1 = i >> 1;
        int n = (c0 + f) + (o1 << 9);
        float sn, cs; __sincosf(PIF * ((float)n * invL), &sn, &cs);
        float2 yE = r[(f << 9) + o1];
        float2 yO = r[((f + 2) << 9) + o1];
        // y = (yE + Re(e^{+i pi n/L} * yO)) / (2L) + D*u
        out[n] = fmaf(D, u[n], (yE.x + cs * yO.x - sn * yO.y) * sc);
    }
}

extern "C" void kernel_launch(void* const* d_in, const int* in_sizes, int n_in,
                              void* d_out, int out_size, void* d_ws, size_t ws_size,
                              hipStream_t stream) {
    const float* u    = (const float*)d_in[0];
    const float* Lre  = (const float*)d_in[1];
    const float* Lim  = (const float*)d_in[2];
    const float* Pre  = (const float*)d_in[3];
    const float* Pim  = (const float*)d_in[4];
    const float* Bre  = (const float*)d_in[5];
    const float* Bim  = (const float*)d_in[6];
    const float* Cri  = (const float*)d_in[7];
    const float* Dp   = (const float*)d_in[8];
    const float* lstp = (const float*)d_in[9];
    float* out = (float*)d_out;

    char* ws = (char*)d_ws;                        // 10 x 2MB = 20 MB
    float2* Acm  = (float2*)(ws);
    float2* T_K  = (float2*)(ws + ( 2u << 20));
    float2* T_U  = (float2*)(ws + ( 4u << 20));
    float2* T_Ko = (float2*)(ws + ( 6u << 20));
    float2* T_Uo = (float2*)(ws + ( 8u << 20));
    float2* Ue   = (float2*)(ws + (10u << 20));
    float2* Uo   = (float2*)(ws + (12u << 20));
    float2* Ko   = (float2*)(ws + (14u << 20));
    float2* T_Ve = (float2*)(ws + (16u << 20));
    float2* T_Vo = (float2*)(ws + (18u << 20));

    kA<<<512, TPB, 0, stream>>>(u, Lre,Lim,Pre,Pim,Bre,Bim,Cri,lstp, Acm, T_K, T_U);
    kB<<<512, TPB, 0, stream>>>(u, T_K, T_Ko, T_Uo);
    kC<<<768, TPB, 0, stream>>>(T_U, T_Uo, T_Ko, Ue, Uo, Ko);
    kD<<<512, TPB, 0, stream>>>(Ue, Uo, Ko, Acm, T_Ve, T_Vo);
    kE<<<256, TPB, 0, stream>>>(T_Ve, T_Vo, u, Dp, out);
}

// Round 7
// 124.018 us; speedup vs baseline: 2.9175x; 1.0899x over previous
//
#include <hip/hip_runtime.h>
#include <math.h>

#define L_LEN  262144          // L = 2^18 = 512*512
#define NST    64
#define TPB    256
#define PI2F   6.2831853071795864769f
#define PIF    3.1415926535897932385f

__device__ inline float2 cmul(float2 a, float2 b) {
    return make_float2(a.x*b.x - a.y*b.y, a.x*b.y + a.y*b.x);
}

// NF independent length-M FFTs in LDS, radix-4 Stockham + final radix-2.
// Layout buf[f*M+i]; natural in/out; sgn=-1 fwd, +1 inv (unscaled).
// Starts and ends with __syncthreads().
template<int M, int NF>
__device__ float2* lds_fft_r4(float2* b0, float2* b1, float sgn) {
    float2* src = b0; float2* dst = b1;
    int Ns = 1;
    while (Ns * 4 <= M) {
        __syncthreads();
        const int NB = NF * (M / 4);
        for (int bi = threadIdx.x; bi < NB; bi += TPB) {
            int f = bi / (M / 4);
            int j = bi & (M / 4 - 1);
            int r = j & (Ns - 1);
            const float2* s = src + f * M;
            float2 x0 = s[j];
            float2 x1 = s[j +     (M/4)];
            float2 x2 = s[j + 2 * (M/4)];
            float2 x3 = s[j + 3 * (M/4)];
            float ang = sgn * PI2F * ((float)r / (float)(4 * Ns));
            float sn, cs; __sincosf(ang, &sn, &cs);
            float2 w1 = make_float2(cs, sn);
            float2 w2 = cmul(w1, w1);
            float2 w3 = cmul(w2, w1);
            x1 = cmul(x1, w1); x2 = cmul(x2, w2); x3 = cmul(x3, w3);
            float2 t0 = make_float2(x0.x + x2.x, x0.y + x2.y);
            float2 t1 = make_float2(x0.x - x2.x, x0.y - x2.y);
            float2 t2 = make_float2(x1.x + x3.x, x1.y + x3.y);
            float2 t3 = make_float2(x1.x - x3.x, x1.y - x3.y);
            float2* d = dst + f * M + ((j - r) << 2) + r;
            d[0]      = make_float2(t0.x + t2.x, t0.y + t2.y);
            d[Ns]     = make_float2(t1.x - sgn * t3.y, t1.y + sgn * t3.x);
            d[2 * Ns] = make_float2(t0.x - t2.x, t0.y - t2.y);
            d[3 * Ns] = make_float2(t1.x + sgn * t3.y, t1.y - sgn * t3.x);
        }
        float2* t = src; src = dst; dst = t;
        Ns <<= 2;
    }
    if (Ns < M) {
        __syncthreads();
        const int NB = NF * (M / 2);
        for (int bi = threadIdx.x; bi < NB; bi += TPB) {
            int f = bi / (M / 2);
            int j = bi & (M / 2 - 1);
            const float2* s = src + f * M;
            float2 a = s[j];
            float2 b = s[j + M / 2];
            float ang = sgn * PI2F * ((float)j / (float)M);
            float sn, cs; __sincosf(ang, &sn, &cs);
            float2 wb = make_float2(cs * b.x - sn * b.y, cs * b.y + sn * b.x);
            float2* d = dst + f * M + j;
            d[0]     = make_float2(a.x + wb.x, a.y + wb.y);
            d[M / 2] = make_float2(a.x - wb.x, a.y - wb.y);
        }
        float2* t = src; src = dst; dst = t;
    }
    __syncthreads();
    return src;
}

// Staging arrays all 512x512 float2, [col*512 + row]; reads contiguous,
// scattered stores 16B-paired.

// ---- k1: pure atroots, grid 1024, 1 point/thread, Acm[(c<<9)+e] = A[c+512e]
__global__ __launch_bounds__(TPB) void k1_atroots(
    const float* __restrict__ Lre, const float* __restrict__ Lim,
    const float* __restrict__ Pre, const float* __restrict__ Pim,
    const float* __restrict__ Bre, const float* __restrict__ Bim,
    const float* __restrict__ Cri, const float* __restrict__ lstp,
    float2* __restrict__ Acm)
{
    __shared__ float4 cA[NST], cB[NST], cC[NST], cD[NST];
    const int t = threadIdx.x, bx = blockIdx.x;
    if (t < NST) {
        float lr = Lre[t], li = Lim[t];
        float pr = Pre[t], pi = Pim[t];
        float br = Bre[t], bi = Bim[t];
        float cr = Cri[2*t], ci = Cri[2*t+1];
        float dx = -lr;
        float v00x = cr*br + ci*bi, v00y = cr*bi - ci*br;   // conj(C)*B
        float v01x = cr*pr + ci*pi, v01y = cr*pi - ci*pr;   // conj(C)*P
        float v10x = pr*br + pi*bi, v10y = pr*bi - pi*br;   // conj(P)*B
        float v11x = pr*pr + pi*pi;                         // conj(P)*P (real)
        cA[t] = make_float4(li, dx*dx, dx*v11x, -v11x);
        cB[t] = make_float4(dx*v00x, v00y, dx*v00y, -v00x);
        cC[t] = make_float4(dx*v01x, v01y, dx*v01y, -v01x);
        cD[t] = make_float4(dx*v10x, v10y, dx*v10y, -v10x);
    }
    __syncthreads();
    const int c = bx >> 1;
    const int e = ((bx & 1) << 8) + t;
    const int j = c + (e << 9);
    const float invL = 1.0f / (float)L_LEN;
    float G2 = 2.0f / expf(lstp[0]);
    // (1-Om)/(1+Om) = i*tan(pi j/L); c_coef = 1+i*tan; g = i*G2*tan
    float h = PIF * ((float)j * invL);
    float sn, cs; __sincosf(h, &sn, &cs);
    float tn = sn * __frcp_rn(cs);
    tn = fminf(fmaxf(tn, -1e7f), 1e7f);   // pole guard (j=L/2: cos==0 exactly)
    float gi = G2 * tn;
    float k00x=0.f,k00y=0.f,k01x=0.f,k01y=0.f,k10x=0.f,k10y=0.f,k11x=0.f,k11y=0.f;
    #pragma unroll 4
    for (int n = 0; n < NST; ++n) {
        float4 a = cA[n];
        float dy   = gi - a.x;
        float iv   = __frcp_rn(fmaf(dy, dy, a.y));   // 1/((dx^2)+dy^2)
        float ivdy = iv * dy;
        // k += (rx + i ry)*v with rx=dx*iv, ry=-dy*iv:
        //   k.x += iv*(dx*vx) + ivdy*vy ; k.y += iv*(dx*vy) - ivdy*vx
        k11x = fmaf(iv, a.z, k11x);  k11y = fmaf(ivdy, a.w, k11y);
        float4 b = cB[n];
        k00x = fmaf(iv, b.x, fmaf(ivdy, b.y, k00x));
        k00y = fmaf(iv, b.z, fmaf(ivdy, b.w, k00y));
        float4 cc = cC[n];
        k01x = fmaf(iv, cc.x, fmaf(ivdy, cc.y, k01x));
        k01y = fmaf(iv, cc.z, fmaf(ivdy, cc.w, k01y));
        float4 d = cD[n];
        k10x = fmaf(iv, d.x, fmaf(ivdy, d.y, k10x));
        k10y = fmaf(iv, d.z, fmaf(ivdy, d.w, k10y));
    }
    float ax = 1.f + k11x, ay = k11y;
    float im = 1.f / (ax*ax + ay*ay);
    float tx = k01x*k10x - k01y*k10y;
    float ty = k01x*k10y + k01y*k10x;
    float wx = k00x - (tx*ax + ty*ay) * im;
    float wy = k00y - (ty*ax - tx*ay) * im;
    Acm[(c << 9) + e] = make_float2(wx - tn*wy, wy + tn*wx);  // (1+i*tan)*w
}

// ---- k2: blocks 0..255: A ifft pass1 -> T_K; 256..511: u & u*tw fwd pass1
__global__ __launch_bounds__(TPB) void k2_pass1(
    const float* __restrict__ u, const float2* __restrict__ Acm,
    float2* __restrict__ T_K, float2* __restrict__ T_U, float2* __restrict__ T_Uo)
{
    __shared__ float2 b0[2048], b1[2048];
    const int t = threadIdx.x, bx = blockIdx.x;
    const int c0 = (bx & 255) << 1;
    const float invL = 1.0f / (float)L_LEN;
    if (bx < 256) {
        for (int i = t; i < 1024; i += TPB)
            b0[i] = Acm[((c0 + (i >> 9)) << 9) + (i & 511)];   // contiguous
        float2* r = lds_fft_r4<512, 2>(b0, b1, +1.f);
        for (int i = t; i < 1024; i += TPB) {
            int f = i & 1, k = i >> 1;
            int c = c0 + f;
            float ang = PI2F * ((float)(c * k) * invL);
            float sn, cs; __sincosf(ang, &sn, &cs);
            T_K[(k << 9) + c] = cmul(make_float2(cs, sn), r[(f << 9) + k]);
        }
    } else {
        for (int i = t; i < 1024; i += TPB) {
            int f = i & 1, e = i >> 1;
            int n = (c0 + f) + (e << 9);
            float uv = u[n];                               // 8B-paired gather
            float sn, cs; __sincosf(PIF * ((float)n * invL), &sn, &cs);
            b0[(f << 9) + e]        = make_float2(uv, 0.f);          // u
            b0[((2 + f) << 9) + e]  = make_float2(uv * cs, -uv * sn); // u*tw
        }
        float2* r = lds_fft_r4<512, 4>(b0, b1, -1.f);
        for (int i = t; i < 2048; i += TPB) {
            int f = i & 1, k = (i >> 1) & 511, v = i >> 10;
            int c = c0 + f;
            float ang = -PI2F * ((float)(c * k) * invL);
            float sn, cs; __sincosf(ang, &sn, &cs);
            float2 val = cmul(make_float2(cs, sn), r[(((v << 1) + f) << 9) + k]);
            if (v == 0) T_U [(k << 9) + c] = val;
            else        T_Uo[(k << 9) + c] = val;
        }
    }
}

// ---- k3: blocks 0..255: T_K pass2 -> K -> K*tw -> fwd pass1 -> T_Ko
//          blocks 256..511: pass2 of T_U,T_Uo -> Ue, Uo ([k1<<9]+k2 contig)
__global__ __launch_bounds__(TPB) void k3_mid(
    const float2* __restrict__ T_K, const float2* __restrict__ T_U,
    const float2* __restrict__ T_Uo,
    float2* __restrict__ T_Ko, float2* __restrict__ Ue, float2* __restrict__ Uo)
{
    __shared__ float2 b0[2048], b1[2048];
    const int t = threadIdx.x, bx = blockIdx.x;
    const int c0 = (bx & 255) << 1;
    const float invL = 1.0f / (float)L_LEN;
    if (bx < 256) {
        for (int i = t; i < 1024; i += TPB)
            b0[i] = T_K[((c0 + (i >> 9)) << 9) + (i & 511)];   // contiguous
        float2* r = lds_fft_r4<512, 2>(b0, b1, +1.f);
        float2* o = (r == b0) ? b1 : b0;
        for (int i = t; i < 1024; i += TPB) {
            int f = i >> 9, o1 = i & 511;
            int n = (c0 + f) + (o1 << 9);
            float K = r[i].x * invL;                       // Re(ifft)/L
            float sn, cs; __sincosf(PIF * ((float)n * invL), &sn, &cs);
            o[i] = make_float2(K * cs, -K * sn);           // K * e^{-i pi n/L}
        }
        float2* r2 = lds_fft_r4<512, 2>(o, r, -1.f);
        for (int i = t; i < 1024; i += TPB) {
            int f = i & 1, k = i >> 1;
            int c = c0 + f;
            float ang = -PI2F * ((float)(c * k) * invL);
            float sn, cs; __sincosf(ang, &sn, &cs);
            T_Ko[(k << 9) + c] = cmul(make_float2(cs, sn), r2[(f << 9) + k]);
        }
    } else {
        for (int i = t; i < 2048; i += TPB) {
            int v = i >> 10, f = (i >> 9) & 1, e = i & 511;
            const float2* Tin = v ? T_Uo : T_U;
            b0[i] = Tin[((c0 + f) << 9) + e];              // contiguous
        }
        float2* r = lds_fft_r4<512, 4>(b0, b1, -1.f);
        for (int i = t; i < 2048; i += TPB) {
            int v = i >> 10, f = (i >> 9) & 1, k2 = i & 511;
            float2* Xo = v ? Uo : Ue;
            Xo[((c0 + f) << 9) + k2] = r[i];               // contiguous
        }
    }
}

// ---- k4: grid 256 (k1 pair): Ko pass2 + Ve=Ue*A, Vo=Uo*Ko + inv pass1
__global__ __launch_bounds__(TPB) void k4_point_inv1(
    const float2* __restrict__ T_Ko, const float2* __restrict__ Ue,
    const float2* __restrict__ Uo, const float2* __restrict__ Acm,
    float2* __restrict__ T_Ve, float2* __restrict__ T_Vo)
{
    __shared__ float2 b0[2048], b1[2048];
    const int t = threadIdx.x, bx = blockIdx.x;
    const int kk0 = bx << 1;
    const float invL = 1.0f / (float)L_LEN;
    for (int i = t; i < 1024; i += TPB)
        b0[i] = T_Ko[((kk0 + (i >> 9)) << 9) + (i & 511)];  // contiguous
    float2* r = lds_fft_r4<512, 2>(b0, b1, -1.f);           // Ko[kc+512*k2]
    float2* o = (r == b0) ? b1 : b0;
    for (int i = t; i < 1024; i += TPB) {
        int f = i >> 9, k2 = i & 511;
        int kc = kk0 + f;
        float2 ko = r[i];
        float2 ue = Ue [(kc << 9) + k2];                    // contiguous
        float2 uo = Uo [(kc << 9) + k2];
        float2 av = Acm[(kc << 9) + k2];
        o[i]        = cmul(ue, av);   // Ve  (Ue Hermitian => Herm(A) not needed)
        o[i + 1024] = cmul(uo, ko);   // Vo
    }
    float2* r2 = lds_fft_r4<512, 4>(o, r, +1.f);
    for (int i = t; i < 2048; i += TPB) {
        int f = i & 1, k = (i >> 1) & 511, v = i >> 10;
        int c = kk0 + f;
        float ang = PI2F * ((float)(c * k) * invL);
        float sn, cs; __sincosf(ang, &sn, &cs);
        float2 val = cmul(make_float2(cs, sn), r2[(((v << 1) + f) << 9) + k]);
        if (v == 0) T_Ve[(k << 9) + c] = val;
        else        T_Vo[(k << 9) + c] = val;
    }
}

// ---- k5: grid 256 (col pair): inv pass2 of T_Ve,T_Vo + combine + D*u + out
__global__ __launch_bounds__(TPB) void k5_out(
    const float2* __restrict__ T_Ve, const float2* __restrict__ T_Vo,
    const float* __restrict__ u, const float* __restrict__ Dp,
    float* __restrict__ out)
{
    __shared__ float2 b0[2048], b1[2048];
    const int t = threadIdx.x, bx = blockIdx.x;
    const int c0 = bx << 1;
    const float invL = 1.0f / (float)L_LEN;
    for (int i = t; i < 1024; i += TPB) {
        int f = i >> 9, m1 = i & 511;
        b0[i]        = T_Ve[((c0 + f) << 9) + m1];          // contiguous
        b0[i + 1024] = T_Vo[((c0 + f) << 9) + m1];
    }
    float2* r = lds_fft_r4<512, 4>(b0, b1, +1.f);           // f<2: yE, f>=2: yO
    const float sc = 0.5f * invL;                           // 1/(2L)
    const float D = Dp[0];
    for (int i = t; i < 1024; i += TPB) {
        int f = i & 1, o1 = i >> 1;
        int n = (c0 + f) + (o1 << 9);
        float sn, cs; __sincosf(PIF * ((float)n * invL), &sn, &cs);
        float2 yE = r[(f << 9) + o1];
        float2 yO = r[((f + 2) << 9) + o1];
        // y = (yE.re + Re(e^{+i pi n/L} * yO)) / (2L) + D*u
        out[n] = fmaf(D, u[n], (yE.x + cs * yO.x - sn * yO.y) * sc);
    }
}

extern "C" void kernel_launch(void* const* d_in, const int* in_sizes, int n_in,
                              void* d_out, int out_size, void* d_ws, size_t ws_size,
                              hipStream_t stream) {
    const float* u    = (const float*)d_in[0];
    const float* Lre  = (const float*)d_in[1];
    const float* Lim  = (const float*)d_in[2];
    const float* Pre  = (const float*)d_in[3];
    const float* Pim  = (const float*)d_in[4];
    const float* Bre  = (const float*)d_in[5];
    const float* Bim  = (const float*)d_in[6];
    const float* Cri  = (const float*)d_in[7];
    const float* Dp   = (const float*)d_in[8];
    const float* lstp = (const float*)d_in[9];
    float* out = (float*)d_out;

    char* ws = (char*)d_ws;                        // 9 x 2MB = 18 MB
    float2* Acm  = (float2*)(ws);
    float2* T_K  = (float2*)(ws + ( 2u << 20));
    float2* T_U  = (float2*)(ws + ( 4u << 20));
    float2* T_Uo = (float2*)(ws + ( 6u << 20));
    float2* T_Ko = (float2*)(ws + ( 8u << 20));
    float2* Ue   = (float2*)(ws + (10u << 20));
    float2* Uo   = (float2*)(ws + (12u << 20));
    float2* T_Ve = (float2*)(ws + (14u << 20));
    float2* T_Vo = (float2*)(ws + (16u << 20));

    k1_atroots <<<1024, TPB, 0, stream>>>(Lre,Lim,Pre,Pim,Bre,Bim,Cri,lstp, Acm);
    k2_pass1   <<< 512, TPB, 0, stream>>>(u, Acm, T_K, T_U, T_Uo);
    k3_mid     <<< 512, TPB, 0, stream>>>(T_K, T_U, T_Uo, T_Ko, Ue, Uo);
    k4_point_inv1<<<256, TPB, 0, stream>>>(T_Ko, Ue, Uo, Acm, T_Ve, T_Vo);
    k5_out     <<< 256, TPB, 0, stream>>>(T_Ve, T_Vo, u, Dp, out);
}

// Round 8
// 117.702 us; speedup vs baseline: 3.0741x; 1.0537x over previous
//
#include <hip/hip_runtime.h>
#include <math.h>

#define L_LEN  262144          // L = 2^18 = 512*512
#define NST    64
#define TPB    256
#define PI2F   6.2831853071795864769f
#define PIF    3.1415926535897932385f

__device__ inline float2 cmul(float2 a, float2 b) {
    return make_float2(a.x*b.x - a.y*b.y, a.x*b.y + a.y*b.x);
}

// NF independent length-M FFTs in LDS, radix-4 Stockham + final radix-2.
// Layout buf[f*M+i]; natural in/out; sgn=-1 fwd, +1 inv (unscaled).
// Starts and ends with __syncthreads().
template<int M, int NF>
__device__ float2* lds_fft_r4(float2* b0, float2* b1, float sgn) {
    float2* src = b0; float2* dst = b1;
    int Ns = 1;
    while (Ns * 4 <= M) {
        __syncthreads();
        const int NB = NF * (M / 4);
        for (int bi = threadIdx.x; bi < NB; bi += TPB) {
            int f = bi / (M / 4);
            int j = bi & (M / 4 - 1);
            int r = j & (Ns - 1);
            const float2* s = src + f * M;
            float2 x0 = s[j];
            float2 x1 = s[j +     (M/4)];
            float2 x2 = s[j + 2 * (M/4)];
            float2 x3 = s[j + 3 * (M/4)];
            float ang = sgn * PI2F * ((float)r / (float)(4 * Ns));
            float sn, cs; __sincosf(ang, &sn, &cs);
            float2 w1 = make_float2(cs, sn);
            float2 w2 = cmul(w1, w1);
            float2 w3 = cmul(w2, w1);
            x1 = cmul(x1, w1); x2 = cmul(x2, w2); x3 = cmul(x3, w3);
            float2 t0 = make_float2(x0.x + x2.x, x0.y + x2.y);
            float2 t1 = make_float2(x0.x - x2.x, x0.y - x2.y);
            float2 t2 = make_float2(x1.x + x3.x, x1.y + x3.y);
            float2 t3 = make_float2(x1.x - x3.x, x1.y - x3.y);
            float2* d = dst + f * M + ((j - r) << 2) + r;
            d[0]      = make_float2(t0.x + t2.x, t0.y + t2.y);
            d[Ns]     = make_float2(t1.x - sgn * t3.y, t1.y + sgn * t3.x);
            d[2 * Ns] = make_float2(t0.x - t2.x, t0.y - t2.y);
            d[3 * Ns] = make_float2(t1.x + sgn * t3.y, t1.y - sgn * t3.x);
        }
        float2* t = src; src = dst; dst = t;
        Ns <<= 2;
    }
    if (Ns < M) {
        __syncthreads();
        const int NB = NF * (M / 2);
        for (int bi = threadIdx.x; bi < NB; bi += TPB) {
            int f = bi / (M / 2);
            int j = bi & (M / 2 - 1);
            const float2* s = src + f * M;
            float2 a = s[j];
            float2 b = s[j + M / 2];
            float ang = sgn * PI2F * ((float)j / (float)M);
            float sn, cs; __sincosf(ang, &sn, &cs);
            float2 wb = make_float2(cs * b.x - sn * b.y, cs * b.y + sn * b.x);
            float2* d = dst + f * M + j;
            d[0]     = make_float2(a.x + wb.x, a.y + wb.y);
            d[M / 2] = make_float2(a.x - wb.x, a.y - wb.y);
        }
        float2* t = src; src = dst; dst = t;
    }
    __syncthreads();
    return src;
}

// Staging arrays 512x512 float2, [(row)<<9 + col]; reads contiguous.

// ---- kI: blocks 0..255: atroots (4 pts/thread, LDS pole tables read once
//          per pole and reused x4) + store Acm + ifft-L pass1 -> T_K.
//          blocks 256..511: u & u*tw fwd pass1 (NF=4) -> T_U, T_Uo.
__global__ __launch_bounds__(TPB) void kI(
    const float* __restrict__ u,
    const float* __restrict__ Lre, const float* __restrict__ Lim,
    const float* __restrict__ Pre, const float* __restrict__ Pim,
    const float* __restrict__ Bre, const float* __restrict__ Bim,
    const float* __restrict__ Cri, const float* __restrict__ lstp,
    float2* __restrict__ Acm, float2* __restrict__ T_K,
    float2* __restrict__ T_U, float2* __restrict__ T_Uo)
{
    __shared__ float2 b0[2048], b1[2048];
    __shared__ float4 cA[NST], cB[NST], cC[NST], cD[NST];
    const int t = threadIdx.x, bx = blockIdx.x;
    const int c0 = (bx & 255) << 1;
    const float invL = 1.0f / (float)L_LEN;
    if (bx < 256) {
        if (t < NST) {
            float lr = Lre[t], li = Lim[t];
            float pr = Pre[t], pi = Pim[t];
            float br = Bre[t], bi = Bim[t];
            float cr = Cri[2*t], ci = Cri[2*t+1];
            float dx = -lr;
            float v00x = cr*br + ci*bi, v00y = cr*bi - ci*br;   // conj(C)*B
            float v01x = cr*pr + ci*pi, v01y = cr*pi - ci*pr;   // conj(C)*P
            float v10x = pr*br + pi*bi, v10y = pr*bi - pi*br;   // conj(P)*B
            float v11x = pr*pr + pi*pi;                         // conj(P)*P
            cA[t] = make_float4(li, dx*dx, dx*v11x, -v11x);
            cB[t] = make_float4(dx*v00x, v00y, dx*v00y, -v00x);
            cC[t] = make_float4(dx*v01x, v01y, dx*v01y, -v01x);
            cD[t] = make_float4(dx*v10x, v10y, dx*v10y, -v10x);
        }
        __syncthreads();
        float G2 = 2.0f / expf(lstp[0]);
        float tn[4], gi[4], acc[4][8];
        #pragma unroll
        for (int p = 0; p < 4; ++p) {
            int i = t + (p << 8);
            int f = i >> 9, e = i & 511;
            int m = (c0 + f) + (e << 9);
            float h = PIF * ((float)m * invL);
            float sn, cs; __sincosf(h, &sn, &cs);
            float tv = sn * __frcp_rn(cs);
            tv = fminf(fmaxf(tv, -1e7f), 1e7f);  // pole guard (m=L/2: cos==0)
            tn[p] = tv; gi[p] = G2 * tv;
            #pragma unroll
            for (int q = 0; q < 8; ++q) acc[p][q] = 0.f;
        }
        #pragma unroll 2
        for (int n = 0; n < NST; ++n) {
            float4 a = cA[n], b = cB[n], cc = cC[n], d = cD[n];
            #pragma unroll
            for (int p = 0; p < 4; ++p) {
                float dy   = gi[p] - a.x;
                float iv   = __frcp_rn(fmaf(dy, dy, a.y));
                float ivdy = iv * dy;
                acc[p][6] = fmaf(iv, a.z, acc[p][6]);
                acc[p][7] = fmaf(ivdy, a.w, acc[p][7]);
                acc[p][0] = fmaf(iv, b.x,  fmaf(ivdy, b.y,  acc[p][0]));
                acc[p][1] = fmaf(iv, b.z,  fmaf(ivdy, b.w,  acc[p][1]));
                acc[p][2] = fmaf(iv, cc.x, fmaf(ivdy, cc.y, acc[p][2]));
                acc[p][3] = fmaf(iv, cc.z, fmaf(ivdy, cc.w, acc[p][3]));
                acc[p][4] = fmaf(iv, d.x,  fmaf(ivdy, d.y,  acc[p][4]));
                acc[p][5] = fmaf(iv, d.z,  fmaf(ivdy, d.w,  acc[p][5]));
            }
        }
        #pragma unroll
        for (int p = 0; p < 4; ++p) {
            int i = t + (p << 8);
            int f = i >> 9, e = i & 511;
            float ax = 1.f + acc[p][6], ay = acc[p][7];
            float im = 1.f / (ax*ax + ay*ay);
            float tx = acc[p][2]*acc[p][4] - acc[p][3]*acc[p][5];
            float ty = acc[p][2]*acc[p][5] + acc[p][3]*acc[p][4];
            float wx = acc[p][0] - (tx*ax + ty*ay) * im;
            float wy = acc[p][1] - (ty*ax - tx*ay) * im;
            float2 A = make_float2(wx - tn[p]*wy, wy + tn[p]*wx); // (1+i*tan)*w
            Acm[((c0 + f) << 9) + e] = A;                // contiguous store
            b0[i] = A;
        }
        float2* r = lds_fft_r4<512, 2>(b0, b1, +1.f);
        for (int i = t; i < 1024; i += TPB) {
            int f = i & 1, k = i >> 1;
            int c = c0 + f;
            float ang = PI2F * ((float)(c * k) * invL);
            float sn, cs; __sincosf(ang, &sn, &cs);
            T_K[(k << 9) + c] = cmul(make_float2(cs, sn), r[(f << 9) + k]);
        }
    } else {
        for (int i = t; i < 1024; i += TPB) {
            int f = i & 1, e = i >> 1;
            int n = (c0 + f) + (e << 9);
            float uv = u[n];                             // 8B-paired gather
            float sn, cs; __sincosf(PIF * ((float)n * invL), &sn, &cs);
            b0[(f << 9) + e]       = make_float2(uv, 0.f);           // u
            b0[((2 + f) << 9) + e] = make_float2(uv * cs, -uv * sn); // u*tw
        }
        float2* r = lds_fft_r4<512, 4>(b0, b1, -1.f);
        for (int i = t; i < 2048; i += TPB) {
            int f = i & 1, k = (i >> 1) & 511, v = i >> 10;
            int c = c0 + f;
            float ang = -PI2F * ((float)(c * k) * invL);
            float sn, cs; __sincosf(ang, &sn, &cs);
            float2 val = cmul(make_float2(cs, sn), r[(((v << 1) + f) << 9) + k]);
            if (v == 0) T_U [(k << 9) + c] = val;
            else        T_Uo[(k << 9) + c] = val;
        }
    }
}

// ---- kII: blocks 0..255: T_K pass2 -> K -> K*tw -> fwd pass1 -> T_Ko
//           blocks 256..511: pass2 of T_U,T_Uo -> Ue, Uo
__global__ __launch_bounds__(TPB) void kII(
    const float2* __restrict__ T_K, const float2* __restrict__ T_U,
    const float2* __restrict__ T_Uo,
    float2* __restrict__ T_Ko, float2* __restrict__ Ue, float2* __restrict__ Uo)
{
    __shared__ float2 b0[2048], b1[2048];
    const int t = threadIdx.x, bx = blockIdx.x;
    const int c0 = (bx & 255) << 1;
    const float invL = 1.0f / (float)L_LEN;
    if (bx < 256) {
        for (int i = t; i < 1024; i += TPB)
            b0[i] = T_K[((c0 + (i >> 9)) << 9) + (i & 511)];   // contiguous
        float2* r = lds_fft_r4<512, 2>(b0, b1, +1.f);
        float2* o = (r == b0) ? b1 : b0;
        for (int i = t; i < 1024; i += TPB) {
            int f = i >> 9, o1 = i & 511;
            int n = (c0 + f) + (o1 << 9);
            float K = r[i].x * invL;                       // Re(ifft)/L
            float sn, cs; __sincosf(PIF * ((float)n * invL), &sn, &cs);
            o[i] = make_float2(K * cs, -K * sn);           // K * e^{-i pi n/L}
        }
        float2* r2 = lds_fft_r4<512, 2>(o, r, -1.f);
        for (int i = t; i < 1024; i += TPB) {
            int f = i & 1, k = i >> 1;
            int c = c0 + f;
            float ang = -PI2F * ((float)(c * k) * invL);
            float sn, cs; __sincosf(ang, &sn, &cs);
            T_Ko[(k << 9) + c] = cmul(make_float2(cs, sn), r2[(f << 9) + k]);
        }
    } else {
        for (int i = t; i < 2048; i += TPB) {
            int v = i >> 10, f = (i >> 9) & 1, e = i & 511;
            const float2* Tin = v ? T_Uo : T_U;
            b0[i] = Tin[((c0 + f) << 9) + e];              // contiguous
        }
        float2* r = lds_fft_r4<512, 4>(b0, b1, -1.f);
        for (int i = t; i < 2048; i += TPB) {
            int v = i >> 10, f = (i >> 9) & 1, k2 = i & 511;
            float2* Xo = v ? Uo : Ue;
            Xo[((c0 + f) << 9) + k2] = r[i];               // contiguous
        }
    }
}

// ---- kIII: grid 512, one row kc/block: Ko pass2 (NF=1) + Ve=Ue*A, Vo=Uo*Ko
//            + inv pass1 (NF=2) -> T_Ve, T_Vo
__global__ __launch_bounds__(TPB) void kIII(
    const float2* __restrict__ T_Ko, const float2* __restrict__ Ue,
    const float2* __restrict__ Uo, const float2* __restrict__ Acm,
    float2* __restrict__ T_Ve, float2* __restrict__ T_Vo)
{
    __shared__ float2 b0[1024], b1[1024];
    const int t = threadIdx.x, kc = blockIdx.x;
    const float invL = 1.0f / (float)L_LEN;
    for (int i = t; i < 512; i += TPB)
        b0[i] = T_Ko[(kc << 9) + i];                        // contiguous
    float2* r = lds_fft_r4<512, 1>(b0, b1, -1.f);           // Ko[kc+512*k2]
    float2* o = (r == b0) ? b1 : b0;
    for (int i = t; i < 512; i += TPB) {
        float2 ko = r[i];
        float2 ue = Ue [(kc << 9) + i];                     // contiguous
        float2 uo = Uo [(kc << 9) + i];
        float2 av = Acm[(kc << 9) + i];
        o[i]       = cmul(ue, av);   // Ve (Ue Hermitian => Herm(A) not needed)
        o[i + 512] = cmul(uo, ko);   // Vo
    }
    float2* r2 = lds_fft_r4<512, 2>(o, r, +1.f);
    for (int i = t; i < 1024; i += TPB) {
        int v = i >> 9, k = i & 511;
        float ang = PI2F * ((float)(kc * k) * invL);
        float sn, cs; __sincosf(ang, &sn, &cs);
        float2 val = cmul(make_float2(cs, sn), r2[(v << 9) + k]);
        if (v == 0) T_Ve[(k << 9) + kc] = val;
        else        T_Vo[(k << 9) + kc] = val;
    }
}

// ---- kIV: grid 512, one row k/block: inv pass2 (NF=2) + combine + D*u + out
__global__ __launch_bounds__(TPB) void kIV(
    const float2* __restrict__ T_Ve, const float2* __restrict__ T_Vo,
    const float* __restrict__ u, const float* __restrict__ Dp,
    float* __restrict__ out)
{
    __shared__ float2 b0[1024], b1[1024];
    const int t = threadIdx.x, k = blockIdx.x;
    const float invL = 1.0f / (float)L_LEN;
    for (int i = t; i < 512; i += TPB) {
        b0[i]       = T_Ve[(k << 9) + i];                   // contiguous
        b0[i + 512] = T_Vo[(k << 9) + i];
    }
    float2* r = lds_fft_r4<512, 2>(b0, b1, +1.f);           // [0,512)=yE, rest yO
    const float sc = 0.5f * invL;                           // 1/(2L)
    const float D = Dp[0];
    for (int o1 = t; o1 < 512; o1 += TPB) {
        int n = k + (o1 << 9);
        float sn, cs; __sincosf(PIF * ((float)n * invL), &sn, &cs);
        float2 yE = r[o1];
        float2 yO = r[o1 + 512];
        // y = (yE.re + Re(e^{+i pi n/L} * yO)) / (2L) + D*u
        out[n] = fmaf(D, u[n], (yE.x + cs * yO.x - sn * yO.y) * sc);
    }
}

extern "C" void kernel_launch(void* const* d_in, const int* in_sizes, int n_in,
                              void* d_out, int out_size, void* d_ws, size_t ws_size,
                              hipStream_t stream) {
    const float* u    = (const float*)d_in[0];
    const float* Lre  = (const float*)d_in[1];
    const float* Lim  = (const float*)d_in[2];
    const float* Pre  = (const float*)d_in[3];
    const float* Pim  = (const float*)d_in[4];
    const float* Bre  = (const float*)d_in[5];
    const float* Bim  = (const float*)d_in[6];
    const float* Cri  = (const float*)d_in[7];
    const float* Dp   = (const float*)d_in[8];
    const float* lstp = (const float*)d_in[9];
    float* out = (float*)d_out;

    char* ws = (char*)d_ws;                        // 9 x 2MB = 18 MB
    float2* Acm  = (float2*)(ws);
    float2* T_K  = (float2*)(ws + ( 2u << 20));
    float2* T_U  = (float2*)(ws + ( 4u << 20));
    float2* T_Uo = (float2*)(ws + ( 6u << 20));
    float2* T_Ko = (float2*)(ws + ( 8u << 20));
    float2* Ue   = (float2*)(ws + (10u << 20));
    float2* Uo   = (float2*)(ws + (12u << 20));
    float2* T_Ve = (float2*)(ws + (14u << 20));
    float2* T_Vo = (float2*)(ws + (16u << 20));

    kI  <<<512, TPB, 0, stream>>>(u, Lre,Lim,Pre,Pim,Bre,Bim,Cri,lstp,
                                  Acm, T_K, T_U, T_Uo);
    kII <<<512, TPB, 0, stream>>>(T_K, T_U, T_Uo, T_Ko, Ue, Uo);
    kIII<<<512, TPB, 0, stream>>>(T_Ko, Ue, Uo, Acm, T_Ve, T_Vo);
    kIV <<<512, TPB, 0, stream>>>(T_Ve, T_Vo, u, Dp, out);
}